// Round 1
// 361.400 us; speedup vs baseline: 1.0033x; 1.0033x over previous
//
#include <hip/hip_runtime.h>
#include <math.h>

#define KK 128
#define TT 512
#define BB 512
#define TAG_START 126
#define TAG_STOP 127

typedef float v4f __attribute__((ext_vector_type(4)));

// padded x index: quarter q (rows 32q..32q+31) starts at float 40q -> quarter
// bases hit banks {0,8,16,24}: 4 distinct b128 addrs/wave are bank-disjoint.
#define XIDX(r) ((r) + (((r) >> 5) << 3))

// quad_perm DPP add: xor1 = 0xB1 [1,0,3,2], xor2 = 0x4E [2,3,0,1]
__device__ __forceinline__ float quad_add(float x, int ctrl) {
    int yi;
    if (ctrl == 0xB1)
        yi = __builtin_amdgcn_update_dpp(0, __float_as_int(x), 0xB1, 0xF, 0xF, true);
    else
        yi = __builtin_amdgcn_update_dpp(0, __float_as_int(x), 0x4E, 0xF, 0xF, true);
    return x + __int_as_float(yi);
}

// Per-step barrier that does NOT drain vmcnt: only LDS (lgkmcnt) must be
// complete for the xs/As double-buffer handoff. __syncthreads() would emit
// s_waitcnt vmcnt(0) and serialize every step on the just-issued emission
// prefetch (HBM ~900cy) -- the whole point of the 8-deep prefetch is to keep
// those loads in flight across the barrier.
#define STEP_BARRIER() asm volatile("s_waitcnt lgkmcnt(0)\n\ts_barrier" ::: "memory")

// ws layout: floats fwd [0,512), gold [512,1024); ints order [1024,1536)

// Descending-length rank (LPT schedule): order[r] = seq index with rank r.
__global__ __launch_bounds__(512) void order_kernel(const int* __restrict__ lengths,
                                                    int* __restrict__ order) {
    __shared__ int L[BB];
    int tid = threadIdx.x;
    L[tid] = lengths[tid];
    __syncthreads();
    int mylen = L[tid];
    int r = 0;
    for (int i = 0; i < BB; i++) {
        int li = L[i];
        r += (li > mylen) || (li == mylen && i < tid);
    }
    order[r] = tid;
}

// Blocks 0..511: forward recursion for seq b = order[blockIdx.x] (longest first).
//   512 threads = 8 waves. wave w, lane l: kq = l&3, row = 16w + (l>>2).
//   Thread holds E[row][32kq..+32) in 32 regs (volatile-asm pinned, AGPR-side).
//   K-reduce = 2 DPP quad_perm adds (VALU, ~10cy — replaces ds_permute shfls).
//   x-write chain is y*fac with fac=exp(em+Mj+A-Sn) precomputed in dot shadow;
//   log only feeds As/terminal (off-chain). ONE lgkmcnt-only barrier/step
//   (keeps the 8-deep emission prefetch in flight); xs dbuf.
// Blocks 512..1023: gold score for seq b-512.
__global__ __launch_bounds__(512, 4) void fused_kernel(
    const float* __restrict__ feats, const float* __restrict__ trans,
    const int* __restrict__ tags, const int* __restrict__ lengths,
    const int* __restrict__ order,
    float* __restrict__ fwd_out, float* __restrict__ gold_out) {
    int tid = threadIdx.x;

    if (blockIdx.x < BB) {
        // ---------------- forward path ----------------
        int b = order[blockIdx.x];
        int w = tid >> 6;
        int l = tid & 63;
        int kq = l & 3;
        int row = 16 * w + (l >> 2);

        __shared__ __align__(16) float xs[2][160];   // padded (XIDX)
        __shared__ float As[2];
        __shared__ float redm[8], reds[8];

        // --- pin E quarter-row (32 floats) via volatile asm loads ---
        const float* tp = trans + row * KK + 32 * kq;
        v4f tv[8];
#pragma unroll
        for (int q = 0; q < 8; q++) {
            asm volatile("global_load_dwordx4 %0, %1, off"
                         : "=v"(tv[q]) : "v"(tp + 4 * q));
        }
        int len = lengths[b];
        const float* fbr = feats + (size_t)b * TT * KK + row;
        asm volatile("s_waitcnt vmcnt(0)"
                     : "+v"(tv[0]), "+v"(tv[1]), "+v"(tv[2]), "+v"(tv[3]),
                       "+v"(tv[4]), "+v"(tv[5]), "+v"(tv[6]), "+v"(tv[7]));

        // full-row max: 32-local -> quad reduce (kq partners are quad lanes)
        float m32 = -1e30f;
#pragma unroll
        for (int q = 0; q < 8; q++)
            m32 = fmaxf(m32, fmaxf(fmaxf(tv[q].x, tv[q].y), fmaxf(tv[q].z, tv[q].w)));
        m32 = fmaxf(m32, __shfl_xor(m32, 1));
        float Mj = fmaxf(m32, __shfl_xor(m32, 2));

        float Erow[32];
#pragma unroll
        for (int q = 0; q < 8; q++) {
            Erow[4 * q + 0] = __expf(tv[q].x - Mj);
            Erow[4 * q + 1] = __expf(tv[q].y - Mj);
            Erow[4 * q + 2] = __expf(tv[q].z - Mj);
            Erow[4 * q + 3] = __expf(tv[q].w - Mj);
        }

        // init x(0) = exp(alpha0 - 0); one writer per row (quad lane 0)
        if (kq == 0) xs[0][XIDX(row)] = (row == TAG_START) ? 1.0f : 0.0f;
        if (tid == 0) { As[0] = 0.f; As[1] = 0.f; }

        float alpha = 0.f, A = 0.f;
        // rolling 8-deep emission prefetch (hides ~900cy HBM miss latency;
        // stays in flight because the step barrier never drains vmcnt)
        float emb[8];
#pragma unroll
        for (int d = 0; d < 8; d++) {
            int tf = (d < len) ? d : (len - 1);
            emb[d] = fbr[(size_t)tf * KK];
        }
        __syncthreads();

        int tmax = (len + 7) & ~7;
        for (int t0 = 0; t0 < tmax; t0 += 8) {
#pragma unroll
            for (int d = 0; d < 8; d++) {
                int t = t0 + d;
                if (t < len) {                       // block-uniform guard
                    float em = emb[d];
                    int tf = (t + 8 < len) ? (t + 8) : (len - 1);
                    emb[d] = fbr[(size_t)tf * KK];   // issue 8 steps ahead

                    int cur = t & 1, nxt = cur ^ 1;
                    float Sn = As[nxt];              // alpha_0(t-1): shift of x(t+1)
                    float fac = __expf(em + Mj + A - Sn);  // off-chain, in dot shadow
                    const v4f* x4 = (const v4f*)(xs[cur] + 40 * kq);
                    float s0 = 0.f, s1 = 0.f, s2 = 0.f, s3 = 0.f;
#pragma unroll
                    for (int q = 0; q < 8; q++) {
                        v4f xv = x4[q];              // broadcast, bank-disjoint
                        s0 = fmaf(Erow[4 * q + 0], xv.x, s0);
                        s1 = fmaf(Erow[4 * q + 1], xv.y, s1);
                        s2 = fmaf(Erow[4 * q + 2], xv.z, s2);
                        s3 = fmaf(Erow[4 * q + 3], xv.w, s3);
                    }
                    float yq = (s0 + s1) + (s2 + s3);
                    yq = quad_add(yq, 0xB1);         // xor1 (DPP)
                    float y = quad_add(yq, 0x4E);    // xor2 (DPP) -> full row sum
                    if (kq == 0) xs[nxt][XIDX(row)] = y * fac;  // = exp(alpha - Sn)
                    alpha = em + Mj + A + __logf(y); // off-chain: As/terminal only
                    if (tid == 0) As[cur] = alpha;   // shift used at step t+1
                    A = Sn;
                    STEP_BARRIER();                  // lgkmcnt-only barrier per step
                }
            }
        }

        // terminal logsumexp_j( alpha[j] + trans[STOP,j] ); quad lane 0 unique
        float term = (kq == 0) ? (alpha + trans[TAG_STOP * KK + row]) : -1e30f;
        float m = term;
#pragma unroll
        for (int off = 32; off >= 1; off >>= 1) m = fmaxf(m, __shfl_xor(m, off));
        float s = (kq == 0) ? __expf(term - m) : 0.f;
#pragma unroll
        for (int off = 32; off >= 1; off >>= 1) s += __shfl_xor(s, off);
        if (l == 0) { redm[w] = m; reds[w] = s; }
        __syncthreads();
        if (tid == 0) {
            float M2 = redm[0];
            for (int i = 1; i < 8; i++) M2 = fmaxf(M2, redm[i]);
            float S2 = 0.f;
            for (int i = 0; i < 8; i++) S2 += reds[i] * __expf(redm[i] - M2);
            fwd_out[b] = M2 + __logf(S2);
        }
    } else {
        // ---------------- gold path ----------------
        int b = blockIdx.x - BB;
        int len = lengths[b];
        const int* tg = tags + (size_t)b * TT;
        const float* fb = feats + (size_t)b * TT * KK;
        float acc = 0.f;
        for (int i = tid; i <= len; i += 512) {
            int from = (i == 0) ? TAG_START : tg[i - 1];
            int to = (i < len) ? tg[i] : TAG_STOP;
            acc += trans[to * KK + from];
        }
        for (int t = tid; t < len; t += 512)
            acc += fb[(size_t)t * KK + tg[t]];
        __shared__ float sred[8];
#pragma unroll
        for (int off = 32; off >= 1; off >>= 1) acc += __shfl_xor(acc, off);
        if ((tid & 63) == 0) sred[tid >> 6] = acc;
        __syncthreads();
        if (tid == 0) {
            float s = 0.f;
            for (int i = 0; i < 8; i++) s += sred[i];
            gold_out[b] = s;
        }
    }
}

__global__ __launch_bounds__(512) void final_kernel(const float* __restrict__ fwd_s,
                                                    const float* __restrict__ gold_s,
                                                    float* __restrict__ out) {
    int tid = threadIdx.x;
    float v = fabsf(fwd_s[tid] - gold_s[tid]);
#pragma unroll
    for (int off = 32; off >= 1; off >>= 1) v += __shfl_xor(v, off);
    __shared__ float sred[8];
    if ((tid & 63) == 0) sred[tid >> 6] = v;
    __syncthreads();
    if (tid == 0) {
        float s = 0.f;
        for (int i = 0; i < 8; i++) s += sred[i];
        out[0] = s / (float)BB;
    }
}

extern "C" void kernel_launch(void* const* d_in, const int* in_sizes, int n_in,
                              void* d_out, int out_size, void* d_ws, size_t ws_size,
                              hipStream_t stream) {
    const float* feats = (const float*)d_in[0];
    const float* trans = (const float*)d_in[1];
    const int* tags = (const int*)d_in[2];
    const int* lengths = (const int*)d_in[3];

    float* ws = (float*)d_ws;
    float* fwdv = ws;
    float* goldv = ws + BB;
    int* order = (int*)(ws + 2 * BB);

    order_kernel<<<1, 512, 0, stream>>>(lengths, order);
    fused_kernel<<<2 * BB, 512, 0, stream>>>(feats, trans, tags, lengths, order,
                                             fwdv, goldv);
    final_kernel<<<1, 512, 0, stream>>>(fwdv, goldv, (float*)d_out);
}

// Round 3
// 341.140 us; speedup vs baseline: 1.0629x; 1.0594x over previous
//
#include <hip/hip_runtime.h>
#include <math.h>

#define KK 128
#define TT 512
#define BB 512
#define TAG_START 126
#define TAG_STOP 127

typedef float v4f __attribute__((ext_vector_type(4)));

// x layout: chunk c (cols 8c..8c+7) at float offset 8c + 4*(c>>2); for a tag j
// the slot is XI(j) = j + 4*(j>>5). The 16 chunk base addresses tile the 32
// LDS banks at exactly 2-way aliasing (2-way = free, m136). Max XI(127)=139.
#define XI(j) ((j) + (((j) >> 5) << 2))

// DPP move (VALU pipe): quad_perm xor1=0xB1 [1,0,3,2], xor2=0x4E [2,3,0,1];
// row_ror:4=0x124, row_ror:8=0x128 (rotation within 16-lane DPP rows).
template <int CTRL>
__device__ __forceinline__ float dpp_movf(float x) {
    return __int_as_float(
        __builtin_amdgcn_update_dpp(0, __float_as_int(x), CTRL, 0xF, 0xF, true));
}

// lgkmcnt-only barrier: LDS handoff needs lgkm drain; global prefetch loads
// stay in flight (per-thread register dests, no cross-thread hazard).
#define STEP_BARRIER() asm volatile("s_waitcnt lgkmcnt(0)\n\ts_barrier" ::: "memory")

// ws layout (identical footprint to the verified R1 kernel — 1536 floats):
//   floats fwd [0,512), gold [512,1024); ints order [1024,1536)

// Descending-length rank (LPT schedule): order[r] = seq index with rank r.
__global__ __launch_bounds__(512) void order_kernel(const int* __restrict__ lengths,
                                                    int* __restrict__ order) {
    __shared__ int L[BB];
    int tid = threadIdx.x;
    L[tid] = lengths[tid];
    __syncthreads();
    int mylen = L[tid];
    int r = 0;
    for (int i = 0; i < BB; i++) {
        int li = L[i];
        r += (li > mylen) || (li == mylen && i < tid);
    }
    order[r] = tid;
}

// Blocks 0..511: forward recursion for seq b = order[blockIdx.x] (longest first).
// Blocks 512..1023: gold score for seq b-512.
//
// Forward thread mapping (512 thr = 8 waves): wave w, lane l:
//   g = (l>>4)&3 -> row-block rb = 4w+g (rows 4rb..4rb+3); c = l&15 -> col
//   chunk (cols 8c..8c+7). Each thread: 4 rows x 8 cols of E in regs
//   (32 floats), reads 8 x-floats (2 ds_read_b128) per step -- 16 wave-reads
//   per block-step vs 64 in the old (R=1,C=32) layout: 4x less LDS return
//   bandwidth, which the R1 counters implicate as the limiter (~770cy/step
//   of LDS pipe vs ~264cy of VALU; VALUBusy 52%, everything else idle).
// K-reduce: quad_perm xor1/xor2 halving (distributes 4 row-accs so lane
// (b0,b1) owns row 4rb+2b0+b1), then replica sums via row_ror:4 + row_ror:8
// -- all VALU/DPP, no LDS shuffles.
__global__ __launch_bounds__(512, 4) void fused_kernel(
    const float* __restrict__ feats, const float* __restrict__ trans,
    const int* __restrict__ tags, const int* __restrict__ lengths,
    const int* __restrict__ order,
    float* __restrict__ fwd_out, float* __restrict__ gold_out) {
    int tid = threadIdx.x;
    int w = tid >> 6;
    int l = tid & 63;

    if (blockIdx.x < BB) {
        // ---------------- forward path ----------------
        int b = order[blockIdx.x];

        __shared__ __align__(16) float xs[2][160];
        __shared__ float As[2];
        __shared__ float redm[8], reds[8];

        // lane geometry
        int g = (l >> 4) & 3;
        int c = l & 15;
        bool b0 = (l & 1) != 0;
        bool b1 = (l & 2) != 0;
        int row_mine = 16 * w + 4 * g + 2 * (l & 1) + ((l >> 1) & 1);
        int xoff = 8 * c + 4 * (c >> 2);   // float offset of my x chunk
        int xw = XI(row_mine);             // my x write slot
        bool writer = (l & 12) == 0;       // one replica lane per row

        // pin E block (4 rows x 8 cols) via volatile asm loads
        v4f tv[8];
#pragma unroll
        for (int r = 0; r < 4; r++) {
            const float* tp = trans + (16 * w + 4 * g + r) * KK + 8 * c;
            asm volatile("global_load_dwordx4 %0, %1, off"
                         : "=v"(tv[2 * r]) : "v"(tp));
            asm volatile("global_load_dwordx4 %0, %1, off"
                         : "=v"(tv[2 * r + 1]) : "v"(tp + 4));
        }
        int len = lengths[b];
        const float* fbr = feats + (size_t)b * TT * KK + row_mine;
        asm volatile("s_waitcnt vmcnt(0)"
                     : "+v"(tv[0]), "+v"(tv[1]), "+v"(tv[2]), "+v"(tv[3]),
                       "+v"(tv[4]), "+v"(tv[5]), "+v"(tv[6]), "+v"(tv[7]));

        // per-row full-row maxes (reduce across the 16 chunk lanes; l^{1,2,4,8}
        // stays within the same 16-lane group)
        float Mj0, Mj1, Mj2, Mj3;
        {
            float m[4];
#pragma unroll
            for (int r = 0; r < 4; r++) {
                v4f aL = tv[2 * r], aH = tv[2 * r + 1];
                float mm = fmaxf(fmaxf(fmaxf(aL.x, aL.y), fmaxf(aL.z, aL.w)),
                                 fmaxf(fmaxf(aH.x, aH.y), fmaxf(aH.z, aH.w)));
#pragma unroll
                for (int off = 1; off <= 8; off <<= 1)
                    mm = fmaxf(mm, __shfl_xor(mm, off));
                m[r] = mm;
            }
            Mj0 = m[0]; Mj1 = m[1]; Mj2 = m[2]; Mj3 = m[3];
        }
        float Mj_mine = b0 ? (b1 ? Mj3 : Mj2) : (b1 ? Mj1 : Mj0);

        float Erow[32];
#pragma unroll
        for (int r = 0; r < 4; r++) {
            float mr = (r == 0) ? Mj0 : (r == 1) ? Mj1 : (r == 2) ? Mj2 : Mj3;
            Erow[8 * r + 0] = __expf(tv[2 * r].x - mr);
            Erow[8 * r + 1] = __expf(tv[2 * r].y - mr);
            Erow[8 * r + 2] = __expf(tv[2 * r].z - mr);
            Erow[8 * r + 3] = __expf(tv[2 * r].w - mr);
            Erow[8 * r + 4] = __expf(tv[2 * r + 1].x - mr);
            Erow[8 * r + 5] = __expf(tv[2 * r + 1].y - mr);
            Erow[8 * r + 6] = __expf(tv[2 * r + 1].z - mr);
            Erow[8 * r + 7] = __expf(tv[2 * r + 1].w - mr);
        }

        // init x(0) = exp(alpha0 - 0)
        if (writer) xs[0][xw] = (row_mine == TAG_START) ? 1.0f : 0.0f;
        if (tid == 0) { As[0] = 0.f; As[1] = 0.f; }

        float alpha = 0.f, A = 0.f;
        // rolling 8-deep emission prefetch
        float emb[8];
#pragma unroll
        for (int d = 0; d < 8; d++) {
            int tf = (d < len) ? d : (len - 1);
            emb[d] = fbr[(size_t)tf * KK];
        }
        __syncthreads();

        int tmax = (len + 7) & ~7;
        for (int t0 = 0; t0 < tmax; t0 += 8) {
#pragma unroll
            for (int d = 0; d < 8; d++) {
                int t = t0 + d;
                if (t < len) {                       // block-uniform guard
                    float em = emb[d];
                    int tf = (t + 8 < len) ? (t + 8) : (len - 1);
                    emb[d] = fbr[(size_t)tf * KK];   // issue 8 steps ahead

                    int cur = t & 1, nxt = cur ^ 1;
                    float Sn = As[nxt];              // alpha_0(t-1) shift
                    float fac = __expf(em + Mj_mine + A - Sn);
                    const v4f* xp = (const v4f*)(xs[cur] + xoff);
                    v4f xa = xp[0], xb = xp[1];      // 2 b128, 2-way banks
                    float a0 = 0.f, a1 = 0.f, a2 = 0.f, a3 = 0.f;
                    a0 = fmaf(Erow[0], xa.x, a0);  a0 = fmaf(Erow[1], xa.y, a0);
                    a0 = fmaf(Erow[2], xa.z, a0);  a0 = fmaf(Erow[3], xa.w, a0);
                    a0 = fmaf(Erow[4], xb.x, a0);  a0 = fmaf(Erow[5], xb.y, a0);
                    a0 = fmaf(Erow[6], xb.z, a0);  a0 = fmaf(Erow[7], xb.w, a0);
                    a1 = fmaf(Erow[8], xa.x, a1);  a1 = fmaf(Erow[9], xa.y, a1);
                    a1 = fmaf(Erow[10], xa.z, a1); a1 = fmaf(Erow[11], xa.w, a1);
                    a1 = fmaf(Erow[12], xb.x, a1); a1 = fmaf(Erow[13], xb.y, a1);
                    a1 = fmaf(Erow[14], xb.z, a1); a1 = fmaf(Erow[15], xb.w, a1);
                    a2 = fmaf(Erow[16], xa.x, a2); a2 = fmaf(Erow[17], xa.y, a2);
                    a2 = fmaf(Erow[18], xa.z, a2); a2 = fmaf(Erow[19], xa.w, a2);
                    a2 = fmaf(Erow[20], xb.x, a2); a2 = fmaf(Erow[21], xb.y, a2);
                    a2 = fmaf(Erow[22], xb.z, a2); a2 = fmaf(Erow[23], xb.w, a2);
                    a3 = fmaf(Erow[24], xa.x, a3); a3 = fmaf(Erow[25], xa.y, a3);
                    a3 = fmaf(Erow[26], xa.z, a3); a3 = fmaf(Erow[27], xa.w, a3);
                    a3 = fmaf(Erow[28], xb.x, a3); a3 = fmaf(Erow[29], xb.y, a3);
                    a3 = fmaf(Erow[30], xb.z, a3); a3 = fmaf(Erow[31], xb.w, a3);
                    // xor1 halving (keep by bit0): even lanes keep rows 0,1
                    float k0 = b0 ? a2 : a0;
                    float k1 = b0 ? a3 : a1;
                    float s0 = b0 ? a0 : a2;
                    float s1 = b0 ? a1 : a3;
                    k0 += dpp_movf<0xB1>(s0);
                    k1 += dpp_movf<0xB1>(s1);
                    // xor2 halving (keep by bit1)
                    float kk = b1 ? k1 : k0;
                    float ss = b1 ? k0 : k1;
                    kk += dpp_movf<0x4E>(ss);
                    // replica sums across lanes {+4,+8,+12} (mod-16 rotation)
                    kk += dpp_movf<0x124>(kk);       // row_ror:4
                    kk += dpp_movf<0x128>(kk);       // row_ror:8
                    if (writer) xs[nxt][xw] = kk * fac;
                    alpha = em + Mj_mine + A + __logf(kk);
                    if (tid == 0) As[cur] = alpha;   // row 0's alpha
                    A = Sn;
                    STEP_BARRIER();
                }
            }
        }

        // terminal logsumexp_j( alpha[j] + trans[STOP,j] ); writer lanes unique
        float term = writer ? (alpha + trans[TAG_STOP * KK + row_mine]) : -1e30f;
        float m = term;
#pragma unroll
        for (int off = 32; off >= 1; off >>= 1) m = fmaxf(m, __shfl_xor(m, off));
        float s = writer ? __expf(term - m) : 0.f;
#pragma unroll
        for (int off = 32; off >= 1; off >>= 1) s += __shfl_xor(s, off);
        if (l == 0) { redm[w] = m; reds[w] = s; }
        __syncthreads();
        if (tid == 0) {
            float M2 = redm[0];
            for (int i = 1; i < 8; i++) M2 = fmaxf(M2, redm[i]);
            float S2 = 0.f;
            for (int i = 0; i < 8; i++) S2 += reds[i] * __expf(redm[i] - M2);
            fwd_out[b] = M2 + __logf(S2);
        }
    } else {
        // ---------------- gold path ----------------
        int b = blockIdx.x - BB;
        int len = lengths[b];
        const int* tg = tags + (size_t)b * TT;
        const float* fb = feats + (size_t)b * TT * KK;
        float acc = 0.f;
        for (int i = tid; i <= len; i += 512) {
            int from = (i == 0) ? TAG_START : tg[i - 1];
            int to = (i < len) ? tg[i] : TAG_STOP;
            acc += trans[to * KK + from];
        }
        for (int t = tid; t < len; t += 512)
            acc += fb[(size_t)t * KK + tg[t]];
        __shared__ float sred[8];
#pragma unroll
        for (int off = 32; off >= 1; off >>= 1) acc += __shfl_xor(acc, off);
        if ((tid & 63) == 0) sred[tid >> 6] = acc;
        __syncthreads();
        if (tid == 0) {
            float s = 0.f;
            for (int i = 0; i < 8; i++) s += sred[i];
            gold_out[b] = s;
        }
    }
}

__global__ __launch_bounds__(512) void final_kernel(const float* __restrict__ fwd_s,
                                                    const float* __restrict__ gold_s,
                                                    float* __restrict__ out) {
    int tid = threadIdx.x;
    float v = fabsf(fwd_s[tid] - gold_s[tid]);
#pragma unroll
    for (int off = 32; off >= 1; off >>= 1) v += __shfl_xor(v, off);
    __shared__ float sred[8];
    if ((tid & 63) == 0) sred[tid >> 6] = v;
    __syncthreads();
    if (tid == 0) {
        float s = 0.f;
        for (int i = 0; i < 8; i++) s += sred[i];
        out[0] = s / (float)BB;
    }
}

extern "C" void kernel_launch(void* const* d_in, const int* in_sizes, int n_in,
                              void* d_out, int out_size, void* d_ws, size_t ws_size,
                              hipStream_t stream) {
    const float* feats = (const float*)d_in[0];
    const float* trans = (const float*)d_in[1];
    const int* tags = (const int*)d_in[2];
    const int* lengths = (const int*)d_in[3];

    float* ws = (float*)d_ws;
    float* fwdv = ws;
    float* goldv = ws + BB;
    int* order = (int*)(ws + 2 * BB);

    order_kernel<<<1, 512, 0, stream>>>(lengths, order);
    fused_kernel<<<2 * BB, 512, 0, stream>>>(feats, trans, tags, lengths, order,
                                             fwdv, goldv);
    final_kernel<<<1, 512, 0, stream>>>(fwdv, goldv, (float*)d_out);
}